// Round 5
// baseline (239.178 us; speedup 1.0000x reference)
//
#include <hip/hip_runtime.h>

// FFB encoder fused kernel, MI355X (gfx950). Round 16.
//  R15 post-mortem: gb-hoist removal cut spills 65->45 MB WRITE (so it WAS a
//  spiller) but ~6 dwords/thread still spill. Remaining suspect (shared by
//  R13-R15): C1 bias-init loads 8 x v4f = 32 VGPRs live at the GEMM1 loop
//  head, overlapping ring(8)+cout(16)+addr(~10) ~= 66-70 > 64 cap.
//  R16:
//   (1) C1 ZERO-init (no loads at loop head); bias added in epilogue:
//       sin_rev(C1 + b[j]), v4f bias quad loaded at use (4 transient regs).
//       Same index math as old init (wcol = w*64+tt*32+8*rq+4*h+j).
//   (2) Layer-0 restructure: was 1 col x 64 rows/thread -> 64 ds_write_u16 +
//       192 LDS reads per wave (~40% of kernel LDS ops). Now wave w owns rows
//       w*16..+15, thread owns cols 4*lane..+3 -> 16 packed b64 stores, pos
//       read from global (wave-uniform, scalarizes), s_pos + its barrier
//       deleted. f32 math identical.
//  Spill tripwire: WRITE ~32.8 MB / FETCH ~14.5 MB, else revert to (256,3)
//  next round (keeping these changes).
//  Kept: GEMM1/grid operand swap, packed b64 epilogue stores, 32x32x16 head,
//  ring-2/dist-1 both GEMMs, K5-prescaled biases, stride-264 LDS.

#define TM 64
#define XSTRIDE 264
#define GSTRIDE 48
#define K5 0.79577471545947667f         // 5/(2*pi)

typedef __attribute__((ext_vector_type(8))) _Float16 v8h;
typedef __attribute__((ext_vector_type(4))) _Float16 v4h;
typedef __attribute__((ext_vector_type(4))) float v4f;
typedef __attribute__((ext_vector_type(16))) float v16f;

#define MFMA32H(a, b, c) __builtin_amdgcn_mfma_f32_32x32x16_f16(a, b, c, 0, 0, 0)

__device__ __forceinline__ float sin_rev(float u) {
#if __has_builtin(__builtin_amdgcn_fractf)
    return __builtin_amdgcn_sinf(__builtin_amdgcn_fractf(u));
#else
    return __builtin_amdgcn_sinf(u - floorf(u));
#endif
}

__device__ __forceinline__ short f16s(float x) {      // RNE f32->f16
    _Float16 hh = (_Float16)x;
    return __builtin_bit_cast(short, hh);
}

// ---------------- weight packing ----------------
// wh   f16: [l][kb16][nt8][lane64][8]  (327680 shorts), scaled by K5
// whh  f16: [l][kb16][nt2][lane64][8]  (81920 shorts),  scaled by K5  (32-col tiles)
// gf   f16: [l][nt8][lane64][8]        (20480 shorts),  ffnA*2^(l-1)
// bhs  f32: [l][256]  = bh*K5          (1280 floats)
// bhhs f32: [l][64]   = bhh*K5         (320 floats)
__global__ __launch_bounds__(256) void ffb_pack(
    const float* __restrict__ Wh, const float* __restrict__ Whh,
    const float* __restrict__ ffnA,
    const float* __restrict__ bh, const float* __restrict__ bhh,
    short* __restrict__ wh, short* __restrict__ whh, short* __restrict__ gf,
    float* __restrict__ bhs, float* __restrict__ bhhs)
{
    int t = blockIdx.x * 256 + threadIdx.x;
    if (t < 40960) {                       // (l, kb, nt, lane)
        int lane = t & 63, nt = (t >> 6) & 7, kb = (t >> 9) & 15, l = t >> 13;
        int n = nt * 32 + (lane & 31);
        int k0 = kb * 16 + (lane >> 5) * 8;
        short hs[8];
        #pragma unroll
        for (int jj = 0; jj < 8; jj++)
            hs[jj] = f16s(Wh[(l * 256 + k0 + jj) * 256 + n] * K5);
        *(v8h*)(wh + t * 8) = *(v8h*)hs;
    } else if (t < 51200) {
        int t2 = t - 40960;                // (l, kb16, nt2, lane)
        int lane = t2 & 63, nt = (t2 >> 6) & 1, kb = (t2 >> 7) & 15, l = t2 >> 11;
        int n = nt * 32 + (lane & 31);
        int k0 = kb * 16 + (lane >> 5) * 8;
        short hs[8];
        #pragma unroll
        for (int jj = 0; jj < 8; jj++)
            hs[jj] = f16s(Whh[(l * 256 + k0 + jj) * 64 + n] * K5);
        *(v8h*)(whh + t2 * 8) = *(v8h*)hs;
    } else if (t < 53760) {
        int t3 = t - 51200;                // (l, nt, lane)
        int lane = t3 & 63, nt = (t3 >> 6) & 7, l = t3 >> 9;
        int n = nt * 32 + (lane & 31);
        const float sc = 0.5f * (float)(1 << l);       // 2^(l-1), exact
        short hs[8];
        #pragma unroll
        for (int jj = 0; jj < 8; jj++)
            hs[jj] = f16s(ffnA[(l * 8 + jj) * 256 + n] * sc);
        *(v8h*)(gf + t3 * 8) = *(v8h*)hs;
    } else if (t < 55040) {
        int t4 = t - 53760;
        bhs[t4] = bh[t4] * K5;
    } else if (t < 55360) {
        int t5 = t - 55040;
        bhhs[t5] = bhh[t5] * K5;
    }
}

// ---------------- main fused kernel ----------------
__global__ __launch_bounds__(256, 4) void ffb_main(
    const float* __restrict__ pos, const float* __restrict__ gfeat,
    const float* __restrict__ W0, const float* __restrict__ b0,
    const float* __restrict__ bhs, const float* __restrict__ bhhs,
    const short* __restrict__ wh, const short* __restrict__ whh,
    const short* __restrict__ gf,
    float* __restrict__ out)
{
    __shared__ __align__(16) short s_x[TM * XSTRIDE];   // f16  (33792 B)
    __shared__ __align__(16) short s_g[TM * GSTRIDE];   // f16  (6144 B)

    const int tid = threadIdx.x;
    const int row0 = blockIdx.x * TM;
    const int lane = tid & 63;
    const int w = tid >> 6;
    const int m32 = lane & 31;
    const int h = lane >> 5;
    const int mq = w >> 1;                 // head-GEMM quadrant row-tile
    const int tq = w & 1;                  // head-GEMM quadrant col-tile

    for (int k2 = tid; k2 < TM * 40; k2 += 256) {
        int r = k2 / 40, f = k2 % 40;
        s_g[r * GSTRIDE + f] = f16s(gfeat[row0 * 40 + k2]);
    }

    // layer 0: x = sin(5*(pos@W0 + b0)); wave w = rows w*16..+15,
    // thread = cols 4*lane..+3; f32 math (identical to pre-R16); packed
    // b64 stores (byte addr = row*528 + lane*8 -> 2-way bank alias, free).
    {
        const int c0 = 4 * lane;
        const int r0 = w * 16;
        float w0c[3][4], bq[4];
        #pragma unroll
        for (int j = 0; j < 4; j++) {
            w0c[0][j] = W0[c0 + j];
            w0c[1][j] = W0[256 + c0 + j];
            w0c[2][j] = W0[512 + c0 + j];
            bq[j] = b0[c0 + j];
        }
        #pragma unroll 4
        for (int r = 0; r < 16; r++) {
            const float p0 = pos[(row0 + r0 + r) * 3 + 0];   // wave-uniform
            const float p1 = pos[(row0 + r0 + r) * 3 + 1];
            const float p2 = pos[(row0 + r0 + r) * 3 + 2];
            v4h pv;
            #pragma unroll
            for (int j = 0; j < 4; j++) {
                float d = p0 * w0c[0][j] + p1 * w0c[1][j] + p2 * w0c[2][j] + bq[j];
                pv[j] = (_Float16)sin_rev(d * K5);
            }
            *(v4h*)(s_x + (r0 + r) * XSTRIDE + c0) = pv;
        }
    }
    __syncthreads();

    float cout[16];
    #pragma unroll
    for (int r = 0; r < 16; r++) cout[r] = 0.f;

    const int a1off0 = m32 * XSTRIDE + h * 8;            // x-row tile 0, + kb*16
    const int a1off1 = (32 + m32) * XSTRIDE + h * 8;     // x-row tile 1

    for (int l = 0; l < 5; l++) {
        // ---- C1 ZERO-init (bias added in epilogue -- no load spike here) ----
        v16f C1[2][2];
        #pragma unroll
        for (int r = 0; r < 16; r++) {
            C1[0][0][r] = 0.f; C1[0][1][r] = 0.f;
            C1[1][0][r] = 0.f; C1[1][1][r] = 0.f;
        }

        // ---- GEMM1 (swapped): wh-frag = A, x-frag = B; depth-2 B-ring ----
        {
            const short* bp = wh + l * 65536 + (2 * w) * 512 + lane * 8;
            v8h rb0[2], rb1[2];
            rb0[0] = *(const v8h*)(bp);
            rb1[0] = *(const v8h*)(bp + 512);
            #pragma unroll
            for (int kb = 0; kb < 16; kb++) {
                if (kb + 1 < 16) {
                    rb0[(kb + 1) & 1] = *(const v8h*)(bp + (kb + 1) * 4096);
                    rb1[(kb + 1) & 1] = *(const v8h*)(bp + (kb + 1) * 4096 + 512);
                }
                v8h a0 = *(const v8h*)&s_x[a1off0 + kb * 16];
                v8h a1 = *(const v8h*)&s_x[a1off1 + kb * 16];
                v8h bc0 = rb0[kb & 1], bc1 = rb1[kb & 1];
                C1[0][0] = MFMA32H(bc0, a0, C1[0][0]);
                C1[0][1] = MFMA32H(bc1, a0, C1[0][1]);
                C1[1][0] = MFMA32H(bc0, a1, C1[1][0]);
                C1[1][1] = MFMA32H(bc1, a1, C1[1][1]);
            }
        }
        __syncthreads();   // all waves done reading x_l

        // ---- epilogue: x = sin(C1 + bias) + sin(G); bias v4f loaded at use;
        //      lane = fixed x-row, reg quads = 4 consecutive W-cols ->
        //      packed b64 stores ----
        {
            v8h gb0 = *(const v8h*)(gf + ((l * 8 + w * 2 + 0) * 64 + lane) * 8);
            v8h gb1 = *(const v8h*)(gf + ((l * 8 + w * 2 + 1) * 64 + lane) * 8);
            const float* bl = bhs + l * 256 + w * 64 + h * 4;
            #pragma unroll
            for (int m = 0; m < 2; m++) {
                v8h ga = *(const v8h*)&s_g[(m * 32 + m32) * GSTRIDE + l * 8];
                const int rowb = (m * 32 + m32) * XSTRIDE;
                #pragma unroll
                for (int tt = 0; tt < 2; tt++) {
                    v16f Z = {};
                    v16f G = MFMA32H((tt ? gb1 : gb0), ga, Z);
                    const int cb = rowb + w * 64 + tt * 32 + h * 4;
                    #pragma unroll
                    for (int rq = 0; rq < 4; rq++) {
                        v4f b = *(const v4f*)(bl + tt * 32 + rq * 8);
                        v4h pv;
                        #pragma unroll
                        for (int j = 0; j < 4; j++)
                            pv[j] = (_Float16)(sin_rev(C1[m][tt][rq * 4 + j] + b[j])
                                             + sin_rev(G[rq * 4 + j]));
                        *(v4h*)(s_x + cb + rq * 8) = pv;    // 8B aligned
                    }
                }
            }
        }
        __syncthreads();   // new x visible

        // ---- head GEMM, 32x32x16: wave = quadrant (mq,tq); x = A (reuses
        //      a1off bases), whh 32-col tiles = B; ring-2/dist-1 (8 VGPRs) ----
        {
            const float b2 = bhhs[l * 64 + tq * 32 + m32];
            v16f C2;
            #pragma unroll
            for (int r = 0; r < 16; r++) C2[r] = b2;
            const short* bp2 = whh + l * 16384 + tq * 512 + lane * 8;
            v8h bc[2];
            bc[0] = *(const v8h*)(bp2);
            const int aoff = mq ? a1off1 : a1off0;
            #pragma unroll
            for (int kb = 0; kb < 16; kb++) {
                if (kb + 1 < 16)
                    bc[(kb + 1) & 1] = *(const v8h*)(bp2 + (kb + 1) * 1024);
                v8h a = *(const v8h*)&s_x[aoff + kb * 16];
                C2 = MFMA32H(a, bc[kb & 1], C2);
            }
            #pragma unroll
            for (int r = 0; r < 16; r++) cout[r] += sin_rev(C2[r]);
        }
        // no barrier: next GEMM1 reads same x; overwrites after its own barrier
    }

    // ---- store x_out: row = mq*32 + regpat, col = tq*32 + m32 (32-wide) ----
    #pragma unroll
    for (int r = 0; r < 16; r++) {
        const int orow = row0 + mq * 32 + (r & 3) + 8 * (r >> 2) + 4 * h;
        out[orow * 64 + tq * 32 + m32] = cout[r];
    }
}

extern "C" void kernel_launch(void* const* d_in, const int* in_sizes, int n_in,
                              void* d_out, int out_size, void* d_ws, size_t ws_size,
                              hipStream_t stream) {
    const float* pos   = (const float*)d_in[0];
    const float* gfeat = (const float*)d_in[1];
    const float* ffnA  = (const float*)d_in[2];
    const float* W0    = (const float*)d_in[3];
    const float* b0    = (const float*)d_in[4];
    const float* Wh    = (const float*)d_in[5];
    const float* bh    = (const float*)d_in[6];
    const float* Whh   = (const float*)d_in[7];
    const float* bhh   = (const float*)d_in[8];
    float* out = (float*)d_out;
    const int N = in_sizes[0] / 3;

    // ws: wh 327680 | whh 81920 | gf 20480 shorts, then bhs 1280 | bhhs 320 f32
    short* wh  = (short*)d_ws;
    short* whh = wh + 327680;
    short* gf  = whh + 81920;
    float* bhs  = (float*)(gf + 20480);     // byte offset 860160, 16B aligned
    float* bhhs = bhs + 1280;

    ffb_pack<<<217, 256, 0, stream>>>(Wh, Whh, ffnA, bh, bhh,
                                      wh, whh, gf, bhs, bhhs);
    ffb_main<<<N / TM, 256, 0, stream>>>(pos, gfeat, W0, b0, bhs, bhhs,
                                         wh, whh, gf, out);
}

// Round 7
// 235.188 us; speedup vs baseline: 1.0170x; 1.0170x over previous
//
#include <hip/hip_runtime.h>

// FFB encoder fused kernel, MI355X (gfx950). Round 17b (resubmit; R17 bench
// died on container infra, no data).
//  R16 post-mortem: bias-into-epilogue RAISED spills (45->49MB) -- spill
//  volume tracks EPILOGUE pressure, and at (256,4)'s 64-VGPR arch cap the
//  epilogue can't fit. Four rounds of (256,4) never ran spill-free; occupancy
//  28->38% (with spills) was flat, VALU/MFMA busy unchanged => stall-bound,
//  not occupancy-bound. (256,4) is dead.
//  R17: revert to (256,3) (~170 unified cap, R12 used 144) and spend the
//  headroom on intra-wave latency hiding:
//   (1) GEMM1 B-ring depth-4/dist-3 (R11-proven at this bound).
//   (2) head B-ring depth-4/dist-3 (R14 code).
//   (3) epilogue G-hoist: per m-tile issue BOTH G MFMAs before sin
//       consumption (removes MFMA->sin latency exposure per quadrant).
//   (4) keep R16 wins: packed-b64 layer-0 (no s_pos/extra barrier),
//       zero-init C1 + bias-at-use in epilogue.
//  Tripwire: WRITE ~32.8MB / FETCH ~14.5MB (zero scratch), VGPR 130-168.
//  If dur >= 158 despite clean counters: stalls are structural -> R18 = TM=32
//  double-buffered s_x, 1 barrier/layer redesign.
//  Kept: GEMM1/grid operand swap, packed b64 epilogue stores, 32x32x16 head,
//  K5-prescaled biases, stride-264 LDS (132 dw == 4 mod 32: b128 reads hit
//  every bank exactly 4x = conflict-free floor), 2 barriers/layer.

#define TM 64
#define XSTRIDE 264
#define GSTRIDE 48
#define K5 0.79577471545947667f         // 5/(2*pi)

typedef __attribute__((ext_vector_type(8))) _Float16 v8h;
typedef __attribute__((ext_vector_type(4))) _Float16 v4h;
typedef __attribute__((ext_vector_type(4))) float v4f;
typedef __attribute__((ext_vector_type(16))) float v16f;

#define MFMA32H(a, b, c) __builtin_amdgcn_mfma_f32_32x32x16_f16(a, b, c, 0, 0, 0)

__device__ __forceinline__ float sin_rev(float u) {
#if __has_builtin(__builtin_amdgcn_fractf)
    return __builtin_amdgcn_sinf(__builtin_amdgcn_fractf(u));
#else
    return __builtin_amdgcn_sinf(u - floorf(u));
#endif
}

__device__ __forceinline__ short f16s(float x) {      // RNE f32->f16
    _Float16 hh = (_Float16)x;
    return __builtin_bit_cast(short, hh);
}

// ---------------- weight packing ----------------
// wh   f16: [l][kb16][nt8][lane64][8]  (327680 shorts), scaled by K5
// whh  f16: [l][kb16][nt2][lane64][8]  (81920 shorts),  scaled by K5  (32-col tiles)
// gf   f16: [l][nt8][lane64][8]        (20480 shorts),  ffnA*2^(l-1)
// bhs  f32: [l][256]  = bh*K5          (1280 floats)
// bhhs f32: [l][64]   = bhh*K5         (320 floats)
__global__ __launch_bounds__(256) void ffb_pack(
    const float* __restrict__ Wh, const float* __restrict__ Whh,
    const float* __restrict__ ffnA,
    const float* __restrict__ bh, const float* __restrict__ bhh,
    short* __restrict__ wh, short* __restrict__ whh, short* __restrict__ gf,
    float* __restrict__ bhs, float* __restrict__ bhhs)
{
    int t = blockIdx.x * 256 + threadIdx.x;
    if (t < 40960) {                       // (l, kb, nt, lane)
        int lane = t & 63, nt = (t >> 6) & 7, kb = (t >> 9) & 15, l = t >> 13;
        int n = nt * 32 + (lane & 31);
        int k0 = kb * 16 + (lane >> 5) * 8;
        short hs[8];
        #pragma unroll
        for (int jj = 0; jj < 8; jj++)
            hs[jj] = f16s(Wh[(l * 256 + k0 + jj) * 256 + n] * K5);
        *(v8h*)(wh + t * 8) = *(v8h*)hs;
    } else if (t < 51200) {
        int t2 = t - 40960;                // (l, kb16, nt2, lane)
        int lane = t2 & 63, nt = (t2 >> 6) & 1, kb = (t2 >> 7) & 15, l = t2 >> 11;
        int n = nt * 32 + (lane & 31);
        int k0 = kb * 16 + (lane >> 5) * 8;
        short hs[8];
        #pragma unroll
        for (int jj = 0; jj < 8; jj++)
            hs[jj] = f16s(Whh[(l * 256 + k0 + jj) * 64 + n] * K5);
        *(v8h*)(whh + t2 * 8) = *(v8h*)hs;
    } else if (t < 53760) {
        int t3 = t - 51200;                // (l, nt, lane)
        int lane = t3 & 63, nt = (t3 >> 6) & 7, l = t3 >> 9;
        int n = nt * 32 + (lane & 31);
        const float sc = 0.5f * (float)(1 << l);       // 2^(l-1), exact
        short hs[8];
        #pragma unroll
        for (int jj = 0; jj < 8; jj++)
            hs[jj] = f16s(ffnA[(l * 8 + jj) * 256 + n] * sc);
        *(v8h*)(gf + t3 * 8) = *(v8h*)hs;
    } else if (t < 55040) {
        int t4 = t - 53760;
        bhs[t4] = bh[t4] * K5;
    } else if (t < 55360) {
        int t5 = t - 55040;
        bhhs[t5] = bhh[t5] * K5;
    }
}

// ---------------- main fused kernel ----------------
__global__ __launch_bounds__(256, 3) void ffb_main(
    const float* __restrict__ pos, const float* __restrict__ gfeat,
    const float* __restrict__ W0, const float* __restrict__ b0,
    const float* __restrict__ bhs, const float* __restrict__ bhhs,
    const short* __restrict__ wh, const short* __restrict__ whh,
    const short* __restrict__ gf,
    float* __restrict__ out)
{
    __shared__ __align__(16) short s_x[TM * XSTRIDE];   // f16  (33792 B)
    __shared__ __align__(16) short s_g[TM * GSTRIDE];   // f16  (6144 B)

    const int tid = threadIdx.x;
    const int row0 = blockIdx.x * TM;
    const int lane = tid & 63;
    const int w = tid >> 6;
    const int m32 = lane & 31;
    const int h = lane >> 5;
    const int mq = w >> 1;                 // head-GEMM quadrant row-tile
    const int tq = w & 1;                  // head-GEMM quadrant col-tile

    for (int k2 = tid; k2 < TM * 40; k2 += 256) {
        int r = k2 / 40, f = k2 % 40;
        s_g[r * GSTRIDE + f] = f16s(gfeat[row0 * 40 + k2]);
    }

    // layer 0: x = sin(5*(pos@W0 + b0)); wave w = rows w*16..+15,
    // thread = cols 4*lane..+3; f32 math; packed b64 stores.
    {
        const int c0 = 4 * lane;
        const int r0 = w * 16;
        float w0c[3][4], bq[4];
        #pragma unroll
        for (int j = 0; j < 4; j++) {
            w0c[0][j] = W0[c0 + j];
            w0c[1][j] = W0[256 + c0 + j];
            w0c[2][j] = W0[512 + c0 + j];
            bq[j] = b0[c0 + j];
        }
        #pragma unroll 4
        for (int r = 0; r < 16; r++) {
            const float p0 = pos[(row0 + r0 + r) * 3 + 0];   // wave-uniform
            const float p1 = pos[(row0 + r0 + r) * 3 + 1];
            const float p2 = pos[(row0 + r0 + r) * 3 + 2];
            v4h pv;
            #pragma unroll
            for (int j = 0; j < 4; j++) {
                float d = p0 * w0c[0][j] + p1 * w0c[1][j] + p2 * w0c[2][j] + bq[j];
                pv[j] = (_Float16)sin_rev(d * K5);
            }
            *(v4h*)(s_x + (r0 + r) * XSTRIDE + c0) = pv;
        }
    }
    __syncthreads();

    float cout[16];
    #pragma unroll
    for (int r = 0; r < 16; r++) cout[r] = 0.f;

    const int a1off0 = m32 * XSTRIDE + h * 8;            // x-row tile 0, + kb*16
    const int a1off1 = (32 + m32) * XSTRIDE + h * 8;     // x-row tile 1

    for (int l = 0; l < 5; l++) {
        // ---- C1 ZERO-init (bias added in epilogue) ----
        v16f C1[2][2];
        #pragma unroll
        for (int r = 0; r < 16; r++) {
            C1[0][0][r] = 0.f; C1[0][1][r] = 0.f;
            C1[1][0][r] = 0.f; C1[1][1][r] = 0.f;
        }

        // ---- GEMM1 (swapped): wh-frag = A, x-frag = B; ring-4/dist-3 ----
        {
            const short* bp = wh + l * 65536 + (2 * w) * 512 + lane * 8;
            v8h rb0[4], rb1[4];
            #pragma unroll
            for (int p = 0; p < 3; p++) {
                rb0[p] = *(const v8h*)(bp + p * 4096);
                rb1[p] = *(const v8h*)(bp + p * 4096 + 512);
            }
            #pragma unroll
            for (int kb = 0; kb < 16; kb++) {
                if (kb + 3 < 16) {
                    rb0[(kb + 3) & 3] = *(const v8h*)(bp + (kb + 3) * 4096);
                    rb1[(kb + 3) & 3] = *(const v8h*)(bp + (kb + 3) * 4096 + 512);
                }
                v8h a0 = *(const v8h*)&s_x[a1off0 + kb * 16];
                v8h a1 = *(const v8h*)&s_x[a1off1 + kb * 16];
                v8h bc0 = rb0[kb & 3], bc1 = rb1[kb & 3];
                C1[0][0] = MFMA32H(bc0, a0, C1[0][0]);
                C1[0][1] = MFMA32H(bc1, a0, C1[0][1]);
                C1[1][0] = MFMA32H(bc0, a1, C1[1][0]);
                C1[1][1] = MFMA32H(bc1, a1, C1[1][1]);
            }
        }
        __syncthreads();   // all waves done reading x_l

        // ---- epilogue: x = sin(C1 + bias) + sin(G); per m-tile, BOTH G
        //      MFMAs issued before any sin (latency hidden); bias v4f at use;
        //      packed b64 stores ----
        {
            v8h gb0 = *(const v8h*)(gf + ((l * 8 + w * 2 + 0) * 64 + lane) * 8);
            v8h gb1 = *(const v8h*)(gf + ((l * 8 + w * 2 + 1) * 64 + lane) * 8);
            const float* bl = bhs + l * 256 + w * 64 + h * 4;
            #pragma unroll
            for (int m = 0; m < 2; m++) {
                v8h ga = *(const v8h*)&s_g[(m * 32 + m32) * GSTRIDE + l * 8];
                v16f Z = {};
                v16f G0 = MFMA32H(gb0, ga, Z);
                v16f G1 = MFMA32H(gb1, ga, Z);
                const int rowb = (m * 32 + m32) * XSTRIDE;
                #pragma unroll
                for (int tt = 0; tt < 2; tt++) {
                    const int cb = rowb + w * 64 + tt * 32 + h * 4;
                    #pragma unroll
                    for (int rq = 0; rq < 4; rq++) {
                        v4f b = *(const v4f*)(bl + tt * 32 + rq * 8);
                        v4h pv;
                        #pragma unroll
                        for (int j = 0; j < 4; j++) {
                            float gv = tt ? G1[rq * 4 + j] : G0[rq * 4 + j];
                            pv[j] = (_Float16)(sin_rev(C1[m][tt][rq * 4 + j] + b[j])
                                             + sin_rev(gv));
                        }
                        *(v4h*)(s_x + cb + rq * 8) = pv;    // 8B aligned
                    }
                }
            }
        }
        __syncthreads();   // new x visible

        // ---- head GEMM, 32x32x16: wave = quadrant (mq,tq); x = A (reuses
        //      a1off bases), whh 32-col tiles = B; ring-4/dist-3 ----
        {
            const float b2 = bhhs[l * 64 + tq * 32 + m32];
            v16f C2;
            #pragma unroll
            for (int r = 0; r < 16; r++) C2[r] = b2;
            const short* bp2 = whh + l * 16384 + tq * 512 + lane * 8;
            v8h bc[4];
            #pragma unroll
            for (int p = 0; p < 3; p++)
                bc[p] = *(const v8h*)(bp2 + p * 1024);
            const int aoff = mq ? a1off1 : a1off0;
            #pragma unroll
            for (int kb = 0; kb < 16; kb++) {
                if (kb + 3 < 16)
                    bc[(kb + 3) & 3] = *(const v8h*)(bp2 + (kb + 3) * 1024);
                v8h a = *(const v8h*)&s_x[aoff + kb * 16];
                C2 = MFMA32H(a, bc[kb & 3], C2);
            }
            #pragma unroll
            for (int r = 0; r < 16; r++) cout[r] += sin_rev(C2[r]);
        }
        // no barrier: next GEMM1 reads same x; overwrites after its own barrier
    }

    // ---- store x_out: row = mq*32 + regpat, col = tq*32 + m32 (32-wide) ----
    #pragma unroll
    for (int r = 0; r < 16; r++) {
        const int orow = row0 + mq * 32 + (r & 3) + 8 * (r >> 2) + 4 * h;
        out[orow * 64 + tq * 32 + m32] = cout[r];
    }
}

extern "C" void kernel_launch(void* const* d_in, const int* in_sizes, int n_in,
                              void* d_out, int out_size, void* d_ws, size_t ws_size,
                              hipStream_t stream) {
    const float* pos   = (const float*)d_in[0];
    const float* gfeat = (const float*)d_in[1];
    const float* ffnA  = (const float*)d_in[2];
    const float* W0    = (const float*)d_in[3];
    const float* b0    = (const float*)d_in[4];
    const float* Wh    = (const float*)d_in[5];
    const float* bh    = (const float*)d_in[6];
    const float* Whh   = (const float*)d_in[7];
    const float* bhh   = (const float*)d_in[8];
    float* out = (float*)d_out;
    const int N = in_sizes[0] / 3;

    // ws: wh 327680 | whh 81920 | gf 20480 shorts, then bhs 1280 | bhhs 320 f32
    short* wh  = (short*)d_ws;
    short* whh = wh + 327680;
    short* gf  = whh + 81920;
    float* bhs  = (float*)(gf + 20480);     // byte offset 860160, 16B aligned
    float* bhhs = bhs + 1280;

    ffb_pack<<<217, 256, 0, stream>>>(Wh, Whh, ffnA, bh, bhh,
                                      wh, whh, gf, bhs, bhhs);
    ffb_main<<<N / TM, 256, 0, stream>>>(pos, gfeat, W0, b0, bhs, bhhs,
                                         wh, whh, gf, out);
}

// Round 8
// 229.990 us; speedup vs baseline: 1.0400x; 1.0226x over previous
//
#include <hip/hip_runtime.h>

// FFB encoder fused kernel, MI355X (gfx950). Round 18.
//  R17 post-mortem: (256,3) + ring-4 + G-hoist ran CLEAN (WRITE 32.77MB,
//  FETCH 14.5MB, zero scratch, VGPR 80) but dur flat at 162us -> prefetch
//  depth / occupancy axis is exhausted (R12-R17: 3 blocks clean, 4 blocks
//  always spills, deeper rings neutral, fewer LDS ops neutral).
//  Bottom-up: per wave MFMA ~3.4K cyc, LDS ~2.4K cyc, VALU ~10K+ cyc --
//  dominated by ~784 sin chains (v_fract + v_sin, 1/4-rate trans pipe).
//  R18: DROP THE FRACT. v_sin_f32 does internal range reduction for
//  |u| <~ 256 revolutions (OCML native_sin emits raw v_sin_f32, no fract).
//  Our args: layer-0 ~±1.2 rev; |C1*K5| <= 256*2*0.025 ~ ±13 rev; grid/head
//  smaller. All << 256 -> removing v_fract is exact here. Cuts ~15-20% of
//  the VALU stream (the critical path) at zero structural risk.
//  Tripwire: absmax must stay <= 0.0625; WRITE/FETCH/VGPR unchanged.
//  If dur >= 158: sin-VALU theory also wrong -> structural ceiling.
//  Kept (all R17): GEMM1/grid operand swap, ring-4/dist-3 both GEMMs,
//  epilogue G-hoist, zero-init C1 + bias-at-use, packed-b64 layer-0,
//  32x32x16 head, K5-prescaled biases, stride-264 LDS, 2 barriers/layer.

#define TM 64
#define XSTRIDE 264
#define GSTRIDE 48
#define K5 0.79577471545947667f         // 5/(2*pi)

typedef __attribute__((ext_vector_type(8))) _Float16 v8h;
typedef __attribute__((ext_vector_type(4))) _Float16 v4h;
typedef __attribute__((ext_vector_type(4))) float v4f;
typedef __attribute__((ext_vector_type(16))) float v16f;

#define MFMA32H(a, b, c) __builtin_amdgcn_mfma_f32_32x32x16_f16(a, b, c, 0, 0, 0)

// Raw v_sin_f32: input in revolutions; HW handles range reduction for
// |u| < ~256 rev. All call sites here are bounded well inside that.
__device__ __forceinline__ float sin_hw(float u) {
    return __builtin_amdgcn_sinf(u);
}

__device__ __forceinline__ short f16s(float x) {      // RNE f32->f16
    _Float16 hh = (_Float16)x;
    return __builtin_bit_cast(short, hh);
}

// ---------------- weight packing ----------------
// wh   f16: [l][kb16][nt8][lane64][8]  (327680 shorts), scaled by K5
// whh  f16: [l][kb16][nt2][lane64][8]  (81920 shorts),  scaled by K5  (32-col tiles)
// gf   f16: [l][nt8][lane64][8]        (20480 shorts),  ffnA*2^(l-1)
// bhs  f32: [l][256]  = bh*K5          (1280 floats)
// bhhs f32: [l][64]   = bhh*K5         (320 floats)
__global__ __launch_bounds__(256) void ffb_pack(
    const float* __restrict__ Wh, const float* __restrict__ Whh,
    const float* __restrict__ ffnA,
    const float* __restrict__ bh, const float* __restrict__ bhh,
    short* __restrict__ wh, short* __restrict__ whh, short* __restrict__ gf,
    float* __restrict__ bhs, float* __restrict__ bhhs)
{
    int t = blockIdx.x * 256 + threadIdx.x;
    if (t < 40960) {                       // (l, kb, nt, lane)
        int lane = t & 63, nt = (t >> 6) & 7, kb = (t >> 9) & 15, l = t >> 13;
        int n = nt * 32 + (lane & 31);
        int k0 = kb * 16 + (lane >> 5) * 8;
        short hs[8];
        #pragma unroll
        for (int jj = 0; jj < 8; jj++)
            hs[jj] = f16s(Wh[(l * 256 + k0 + jj) * 256 + n] * K5);
        *(v8h*)(wh + t * 8) = *(v8h*)hs;
    } else if (t < 51200) {
        int t2 = t - 40960;                // (l, kb16, nt2, lane)
        int lane = t2 & 63, nt = (t2 >> 6) & 1, kb = (t2 >> 7) & 15, l = t2 >> 11;
        int n = nt * 32 + (lane & 31);
        int k0 = kb * 16 + (lane >> 5) * 8;
        short hs[8];
        #pragma unroll
        for (int jj = 0; jj < 8; jj++)
            hs[jj] = f16s(Whh[(l * 256 + k0 + jj) * 64 + n] * K5);
        *(v8h*)(whh + t2 * 8) = *(v8h*)hs;
    } else if (t < 53760) {
        int t3 = t - 51200;                // (l, nt, lane)
        int lane = t3 & 63, nt = (t3 >> 6) & 7, l = t3 >> 9;
        int n = nt * 32 + (lane & 31);
        const float sc = 0.5f * (float)(1 << l);       // 2^(l-1), exact
        short hs[8];
        #pragma unroll
        for (int jj = 0; jj < 8; jj++)
            hs[jj] = f16s(ffnA[(l * 8 + jj) * 256 + n] * sc);
        *(v8h*)(gf + t3 * 8) = *(v8h*)hs;
    } else if (t < 55040) {
        int t4 = t - 53760;
        bhs[t4] = bh[t4] * K5;
    } else if (t < 55360) {
        int t5 = t - 55040;
        bhhs[t5] = bhh[t5] * K5;
    }
}

// ---------------- main fused kernel ----------------
__global__ __launch_bounds__(256, 3) void ffb_main(
    const float* __restrict__ pos, const float* __restrict__ gfeat,
    const float* __restrict__ W0, const float* __restrict__ b0,
    const float* __restrict__ bhs, const float* __restrict__ bhhs,
    const short* __restrict__ wh, const short* __restrict__ whh,
    const short* __restrict__ gf,
    float* __restrict__ out)
{
    __shared__ __align__(16) short s_x[TM * XSTRIDE];   // f16  (33792 B)
    __shared__ __align__(16) short s_g[TM * GSTRIDE];   // f16  (6144 B)

    const int tid = threadIdx.x;
    const int row0 = blockIdx.x * TM;
    const int lane = tid & 63;
    const int w = tid >> 6;
    const int m32 = lane & 31;
    const int h = lane >> 5;
    const int mq = w >> 1;                 // head-GEMM quadrant row-tile
    const int tq = w & 1;                  // head-GEMM quadrant col-tile

    for (int k2 = tid; k2 < TM * 40; k2 += 256) {
        int r = k2 / 40, f = k2 % 40;
        s_g[r * GSTRIDE + f] = f16s(gfeat[row0 * 40 + k2]);
    }

    // layer 0: x = sin(5*(pos@W0 + b0)); wave w = rows w*16..+15,
    // thread = cols 4*lane..+3; f32 math; packed b64 stores.
    {
        const int c0 = 4 * lane;
        const int r0 = w * 16;
        float w0c[3][4], bq[4];
        #pragma unroll
        for (int j = 0; j < 4; j++) {
            w0c[0][j] = W0[c0 + j];
            w0c[1][j] = W0[256 + c0 + j];
            w0c[2][j] = W0[512 + c0 + j];
            bq[j] = b0[c0 + j];
        }
        #pragma unroll 4
        for (int r = 0; r < 16; r++) {
            const float p0 = pos[(row0 + r0 + r) * 3 + 0];   // wave-uniform
            const float p1 = pos[(row0 + r0 + r) * 3 + 1];
            const float p2 = pos[(row0 + r0 + r) * 3 + 2];
            v4h pv;
            #pragma unroll
            for (int j = 0; j < 4; j++) {
                float d = p0 * w0c[0][j] + p1 * w0c[1][j] + p2 * w0c[2][j] + bq[j];
                pv[j] = (_Float16)sin_hw(d * K5);
            }
            *(v4h*)(s_x + (r0 + r) * XSTRIDE + c0) = pv;
        }
    }
    __syncthreads();

    float cout[16];
    #pragma unroll
    for (int r = 0; r < 16; r++) cout[r] = 0.f;

    const int a1off0 = m32 * XSTRIDE + h * 8;            // x-row tile 0, + kb*16
    const int a1off1 = (32 + m32) * XSTRIDE + h * 8;     // x-row tile 1

    for (int l = 0; l < 5; l++) {
        // ---- C1 ZERO-init (bias added in epilogue) ----
        v16f C1[2][2];
        #pragma unroll
        for (int r = 0; r < 16; r++) {
            C1[0][0][r] = 0.f; C1[0][1][r] = 0.f;
            C1[1][0][r] = 0.f; C1[1][1][r] = 0.f;
        }

        // ---- GEMM1 (swapped): wh-frag = A, x-frag = B; ring-4/dist-3 ----
        {
            const short* bp = wh + l * 65536 + (2 * w) * 512 + lane * 8;
            v8h rb0[4], rb1[4];
            #pragma unroll
            for (int p = 0; p < 3; p++) {
                rb0[p] = *(const v8h*)(bp + p * 4096);
                rb1[p] = *(const v8h*)(bp + p * 4096 + 512);
            }
            #pragma unroll
            for (int kb = 0; kb < 16; kb++) {
                if (kb + 3 < 16) {
                    rb0[(kb + 3) & 3] = *(const v8h*)(bp + (kb + 3) * 4096);
                    rb1[(kb + 3) & 3] = *(const v8h*)(bp + (kb + 3) * 4096 + 512);
                }
                v8h a0 = *(const v8h*)&s_x[a1off0 + kb * 16];
                v8h a1 = *(const v8h*)&s_x[a1off1 + kb * 16];
                v8h bc0 = rb0[kb & 3], bc1 = rb1[kb & 3];
                C1[0][0] = MFMA32H(bc0, a0, C1[0][0]);
                C1[0][1] = MFMA32H(bc1, a0, C1[0][1]);
                C1[1][0] = MFMA32H(bc0, a1, C1[1][0]);
                C1[1][1] = MFMA32H(bc1, a1, C1[1][1]);
            }
        }
        __syncthreads();   // all waves done reading x_l

        // ---- epilogue: x = sin(C1 + bias) + sin(G); per m-tile, BOTH G
        //      MFMAs issued before any sin (latency hidden); bias v4f at use;
        //      packed b64 stores ----
        {
            v8h gb0 = *(const v8h*)(gf + ((l * 8 + w * 2 + 0) * 64 + lane) * 8);
            v8h gb1 = *(const v8h*)(gf + ((l * 8 + w * 2 + 1) * 64 + lane) * 8);
            const float* bl = bhs + l * 256 + w * 64 + h * 4;
            #pragma unroll
            for (int m = 0; m < 2; m++) {
                v8h ga = *(const v8h*)&s_g[(m * 32 + m32) * GSTRIDE + l * 8];
                v16f Z = {};
                v16f G0 = MFMA32H(gb0, ga, Z);
                v16f G1 = MFMA32H(gb1, ga, Z);
                const int rowb = (m * 32 + m32) * XSTRIDE;
                #pragma unroll
                for (int tt = 0; tt < 2; tt++) {
                    const int cb = rowb + w * 64 + tt * 32 + h * 4;
                    #pragma unroll
                    for (int rq = 0; rq < 4; rq++) {
                        v4f b = *(const v4f*)(bl + tt * 32 + rq * 8);
                        v4h pv;
                        #pragma unroll
                        for (int j = 0; j < 4; j++) {
                            float gv = tt ? G1[rq * 4 + j] : G0[rq * 4 + j];
                            pv[j] = (_Float16)(sin_hw(C1[m][tt][rq * 4 + j] + b[j])
                                             + sin_hw(gv));
                        }
                        *(v4h*)(s_x + cb + rq * 8) = pv;    // 8B aligned
                    }
                }
            }
        }
        __syncthreads();   // new x visible

        // ---- head GEMM, 32x32x16: wave = quadrant (mq,tq); x = A (reuses
        //      a1off bases), whh 32-col tiles = B; ring-4/dist-3 ----
        {
            const float b2 = bhhs[l * 64 + tq * 32 + m32];
            v16f C2;
            #pragma unroll
            for (int r = 0; r < 16; r++) C2[r] = b2;
            const short* bp2 = whh + l * 16384 + tq * 512 + lane * 8;
            v8h bc[4];
            #pragma unroll
            for (int p = 0; p < 3; p++)
                bc[p] = *(const v8h*)(bp2 + p * 1024);
            const int aoff = mq ? a1off1 : a1off0;
            #pragma unroll
            for (int kb = 0; kb < 16; kb++) {
                if (kb + 3 < 16)
                    bc[(kb + 3) & 3] = *(const v8h*)(bp2 + (kb + 3) * 1024);
                v8h a = *(const v8h*)&s_x[aoff + kb * 16];
                C2 = MFMA32H(a, bc[kb & 3], C2);
            }
            #pragma unroll
            for (int r = 0; r < 16; r++) cout[r] += sin_hw(C2[r]);
        }
        // no barrier: next GEMM1 reads same x; overwrites after its own barrier
    }

    // ---- store x_out: row = mq*32 + regpat, col = tq*32 + m32 (32-wide) ----
    #pragma unroll
    for (int r = 0; r < 16; r++) {
        const int orow = row0 + mq * 32 + (r & 3) + 8 * (r >> 2) + 4 * h;
        out[orow * 64 + tq * 32 + m32] = cout[r];
    }
}

extern "C" void kernel_launch(void* const* d_in, const int* in_sizes, int n_in,
                              void* d_out, int out_size, void* d_ws, size_t ws_size,
                              hipStream_t stream) {
    const float* pos   = (const float*)d_in[0];
    const float* gfeat = (const float*)d_in[1];
    const float* ffnA  = (const float*)d_in[2];
    const float* W0    = (const float*)d_in[3];
    const float* b0    = (const float*)d_in[4];
    const float* Wh    = (const float*)d_in[5];
    const float* bh    = (const float*)d_in[6];
    const float* Whh   = (const float*)d_in[7];
    const float* bhh   = (const float*)d_in[8];
    float* out = (float*)d_out;
    const int N = in_sizes[0] / 3;

    // ws: wh 327680 | whh 81920 | gf 20480 shorts, then bhs 1280 | bhhs 320 f32
    short* wh  = (short*)d_ws;
    short* whh = wh + 327680;
    short* gf  = whh + 81920;
    float* bhs  = (float*)(gf + 20480);     // byte offset 860160, 16B aligned
    float* bhhs = bhs + 1280;

    ffb_pack<<<217, 256, 0, stream>>>(Wh, Whh, ffnA, bh, bhh,
                                      wh, whh, gf, bhs, bhhs);
    ffb_main<<<N / TM, 256, 0, stream>>>(pos, gfeat, W0, b0, bhs, bhhs,
                                         wh, whh, gf, out);
}